// Round 1
// baseline (1300.982 us; speedup 1.0000x reference)
//
#include <hip/hip_runtime.h>

#define LL 4096
#define NB 4
#define NC 64
#define NT 4
#define NLAYERS 10

// ---------------- Threefry-2x32, key = (0, 42), 20 rounds ----------------
__device__ __forceinline__ void threefry2x32(unsigned x0, unsigned x1,
                                             unsigned& o0, unsigned& o1) {
  const unsigned ks0 = 0u, ks1 = 42u;
  const unsigned ks2 = 0x1BD11BDAu ^ ks0 ^ ks1;
  const unsigned ks[3] = {ks0, ks1, ks2};
  const unsigned r0[4] = {13u, 15u, 26u, 6u};
  const unsigned r1[4] = {17u, 29u, 16u, 24u};
  x0 += ks0; x1 += ks1;
#pragma unroll
  for (int g = 0; g < 5; ++g) {
    const unsigned* rr = (g & 1) ? r1 : r0;
#pragma unroll
    for (int j = 0; j < 4; ++j) {
      x0 += x1;
      unsigned r = rr[j];
      x1 = (x1 << r) | (x1 >> (32u - r));
      x1 ^= x0;
    }
    x0 += ks[(g + 1) % 3];
    x1 += ks[(g + 2) % 3] + (unsigned)(g + 1);
  }
  o0 = x0; o1 = x1;
}

__device__ __forceinline__ float u01(unsigned bits) {
  return __uint_as_float((bits >> 9) | 0x3f800000u) - 1.0f;
}

// LIF step: v = v + (x - v)/1.2 ; spike = v>=0.5 ; v *= (1-spike)
__device__ __forceinline__ float lif_step(float& v, float xt) {
  v = v + (xt - v) / 1.2f;
  float s = (v >= 0.5f) ? 1.0f : 0.0f;
  v = v * (1.0f - s);
  return s;
}

// ---------------- transpose skip_w / res_w to [i][c'][c] ----------------
__global__ void transpose_w_kernel(const float* __restrict__ skip_w,
                                   const float* __restrict__ res_w,
                                   float* __restrict__ skipT,
                                   float* __restrict__ resT) {
  int i = blockIdx.x;
  for (int idx = threadIdx.x; idx < 4096; idx += 256) {
    int c = idx >> 6, cp = idx & 63;
    skipT[i * 4096 + cp * 64 + c] = skip_w[i * 4096 + c * 64 + cp];
    resT[i * 4096 + cp * 64 + c] = res_w[i * 4096 + c * 64 + cp];
  }
}

// ---------------- diffusion-step embedding -> proj[i][b][c] ----------------
__global__ void proj_kernel(const int* __restrict__ dstep,
                            const float* __restrict__ w1, const float* __restrict__ b1,
                            const float* __restrict__ w2, const float* __restrict__ b2,
                            const float* __restrict__ pw, const float* __restrict__ pb,
                            float* __restrict__ proj) {
  __shared__ float e1[NB][NC];
  __shared__ float e2[NB][NC];
  int i = blockIdx.x;
  int tid = threadIdx.x;
  int b = tid >> 6, c = tid & 63;
  float d = (float)dstep[b];
  float v = d * w1[i * 64 + c] + b1[i * 64 + c];
  v = v / (1.0f + expf(-v));  // silu
  e1[b][c] = v;
  __syncthreads();
  float a = b2[i * 64 + c];
  for (int cp = 0; cp < 64; ++cp) a += e1[b][cp] * w2[(i * 64 + c) * 64 + cp];
  e2[b][c] = a;
  __syncthreads();
  float p = pb[i * 64 + c];
  for (int cp = 0; cp < 64; ++cp) p += e2[b][cp] * pw[(i * 64 + c) * 64 + cp];
  proj[(i * 4 + b) * 64 + c] = p;
}

// ---------------- Poisson encode + input conv + LIF -> x [T][B][C][L] ----------------
__global__ void encode_lif_kernel(const float* __restrict__ audio,
                                  const float* __restrict__ W_in,
                                  const float* __restrict__ b_in,
                                  float* __restrict__ x) {
  int l = blockIdx.x * 256 + threadIdx.x;
  int b = blockIdx.y;
  float a = audio[b * LL + l];
  unsigned p0 = (unsigned)(b * LL + l);       // t=0 (o0), t=2 (o1)
  unsigned p1 = 16384u + p0;                  // t=1 (o0), t=3 (o1)
  unsigned o00, o01, o10, o11;
  threefry2x32(p0, p0 + 32768u, o00, o01);
  threefry2x32(p1, p1 + 32768u, o10, o11);
  float sp[4];
  sp[0] = (u01(o00) < a) ? 1.0f : 0.0f;
  sp[1] = (u01(o10) < a) ? 1.0f : 0.0f;
  sp[2] = (u01(o01) < a) ? 1.0f : 0.0f;
  sp[3] = (u01(o11) < a) ? 1.0f : 0.0f;
  for (int c = 0; c < 64; ++c) {
    float w = W_in[c], bb = b_in[c];
    float v = 0.0f;
#pragma unroll
    for (int t = 0; t < 4; ++t) {
      float xt = w * sp[t] + bb;
      float s = lif_step(v, xt);
      x[((t * 4 + b) * 64 + c) * LL + l] = s;
    }
  }
}

// ---------------- dilated conv + LIF + gate -> y [T][B][64][L] ----------------
// grid (L/64, 4 co-groups, B), block 256 = 4 waves x 64 lanes.
// wave handles 4 gate co (coG*16+wave*4..+3) and the paired filt co (+64).
__global__ __launch_bounds__(256) void layer_conv_kernel(
    const float* __restrict__ x, const float* __restrict__ conv_w,
    const float* __restrict__ conv_b, const float* __restrict__ proj,
    float* __restrict__ y, int layer, int dil) {
  __shared__ float w_lds[64 * 3 * 32];  // [ci*3+k][co_local 0..31] (0-15 gate,16-31 filt)
  __shared__ float proj_lds[64];
  int tid = threadIdx.x;
  int lane = tid & 63, wave = tid >> 6;
  int coG = blockIdx.y;
  int b = blockIdx.z;
  int l = blockIdx.x * 64 + lane;

  for (int idx = tid; idx < 32 * 192; idx += 256) {
    int col = idx / 192;
    int r = idx % 192;  // ci*3+k
    int co = (col < 16) ? (coG * 16 + col) : (64 + coG * 16 + (col - 16));
    w_lds[r * 32 + col] = conv_w[(layer * 128 + co) * 192 + r];
  }
  if (tid < 64) proj_lds[tid] = proj[(layer * 4 + b) * 64 + tid];
  __syncthreads();

  float ag[4][4], af[4][4];
#pragma unroll
  for (int t = 0; t < 4; ++t)
#pragma unroll
    for (int j = 0; j < 4; ++j) { ag[t][j] = 0.0f; af[t][j] = 0.0f; }

  for (int ci = 0; ci < 64; ++ci) {
    float pv = proj_lds[ci];
    float xv[3][4];
#pragma unroll
    for (int k = 0; k < 3; ++k) {
      int pos = l + (k - 1) * dil;
      bool ok = ((unsigned)pos < (unsigned)LL);
      int posc = ok ? pos : 0;
#pragma unroll
      for (int t = 0; t < 4; ++t) {
        float xl = x[((t * 4 + b) * 64 + ci) * LL + posc];
        xv[k][t] = ok ? (xl + pv) : 0.0f;
      }
    }
#pragma unroll
    for (int k = 0; k < 3; ++k) {
      const float4 wg = *(const float4*)&w_lds[(ci * 3 + k) * 32 + wave * 4];
      const float4 wf = *(const float4*)&w_lds[(ci * 3 + k) * 32 + 16 + wave * 4];
#pragma unroll
      for (int t = 0; t < 4; ++t) {
        float xvv = xv[k][t];
        ag[t][0] += wg.x * xvv; ag[t][1] += wg.y * xvv;
        ag[t][2] += wg.z * xvv; ag[t][3] += wg.w * xvv;
        af[t][0] += wf.x * xvv; af[t][1] += wf.y * xvv;
        af[t][2] += wf.z * xvv; af[t][3] += wf.w * xvv;
      }
    }
  }

  const float SIG1 = 0.73105857863000489f;   // sigmoid(1) in fp32
  const float TANH1 = 0.76159415595576486f;  // tanh(1) in fp32
#pragma unroll
  for (int j = 0; j < 4; ++j) {
    int cg = coG * 16 + wave * 4 + j;
    float bg = conv_b[layer * 128 + cg];
    float bf = conv_b[layer * 128 + 64 + cg];
    float vg = 0.0f, vf = 0.0f;
#pragma unroll
    for (int t = 0; t < 4; ++t) {
      float sg = lif_step(vg, ag[t][j] + bg);
      float sf = lif_step(vf, af[t][j] + bf);
      float gv = (sg != 0.0f) ? SIG1 : 0.5f;
      float tv = (sf != 0.0f) ? TANH1 : 0.0f;
      y[((t * 4 + b) * 64 + cg) * LL + l] = gv * tv;
    }
  }
}

// ---------------- fused 1x1 skip & res convs ----------------
// grid (L/64, T, B), block 256 = 4 waves; wave handles c in [wave*16, +16)
__global__ __launch_bounds__(256) void skip_res_kernel(
    const float* __restrict__ y, const float* __restrict__ skipT,
    const float* __restrict__ resT, const float* __restrict__ skip_b,
    const float* __restrict__ res_b, float* __restrict__ tskip,
    float* __restrict__ x, int layer) {
  __shared__ float y_lds[64 * 64];  // [c'][l]
  __shared__ float sw[64 * 64];     // [c'][c]
  __shared__ float rw[64 * 64];
  int tid = threadIdx.x;
  int lane = tid & 63, wave = tid >> 6;
  int l0 = blockIdx.x * 64;
  int t = blockIdx.y;
  int b = blockIdx.z;

  for (int idx = tid; idx < 4096; idx += 256) {
    int cp = idx >> 6, ll = idx & 63;
    y_lds[idx] = y[((t * 4 + b) * 64 + cp) * LL + l0 + ll];
    sw[idx] = skipT[layer * 4096 + idx];
    rw[idx] = resT[layer * 4096 + idx];
  }
  __syncthreads();

  float accs[16], accr[16];
#pragma unroll
  for (int j = 0; j < 16; ++j) { accs[j] = 0.0f; accr[j] = 0.0f; }

  for (int cp = 0; cp < 64; ++cp) {
    float yv = y_lds[cp * 64 + lane];
#pragma unroll
    for (int q = 0; q < 4; ++q) {
      const float4 wsv = *(const float4*)&sw[cp * 64 + wave * 16 + q * 4];
      const float4 wrv = *(const float4*)&rw[cp * 64 + wave * 16 + q * 4];
      accs[q * 4 + 0] += wsv.x * yv; accs[q * 4 + 1] += wsv.y * yv;
      accs[q * 4 + 2] += wsv.z * yv; accs[q * 4 + 3] += wsv.w * yv;
      accr[q * 4 + 0] += wrv.x * yv; accr[q * 4 + 1] += wrv.y * yv;
      accr[q * 4 + 2] += wrv.z * yv; accr[q * 4 + 3] += wrv.w * yv;
    }
  }

#pragma unroll
  for (int j = 0; j < 16; ++j) {
    int c = wave * 16 + j;
    int idx = ((t * 4 + b) * 64 + c) * LL + l0 + lane;
    float sv = accs[j] + skip_b[layer * 64 + c];
    if (layer == 0) tskip[idx] = sv;
    else tskip[idx] = tskip[idx] + sv;
    x[idx] = x[idx] + (accr[j] + res_b[layer * 64 + c]);
  }
}

// ---------------- output conv + LIF + sum over T ----------------
__global__ void out_kernel(const float* __restrict__ tskip,
                           const float* __restrict__ W_out,
                           const float* __restrict__ b_out,
                           float* __restrict__ out) {
  int l = blockIdx.x * 256 + threadIdx.x;
  int b = blockIdx.y;
  float acc[4] = {0.0f, 0.0f, 0.0f, 0.0f};
  for (int c = 0; c < 64; ++c) {
    float w = W_out[c];
#pragma unroll
    for (int t = 0; t < 4; ++t) {
      float sv = tskip[((t * 4 + b) * 64 + c) * LL + l];
      sv = fmaxf(sv, 0.0f);
      acc[t] += sv * w;
    }
  }
  float bo = b_out[0];
  float v = 0.0f, s = 0.0f;
#pragma unroll
  for (int t = 0; t < 4; ++t) {
    s += lif_step(v, acc[t] + bo);
  }
  out[b * LL + l] = s;
}

extern "C" void kernel_launch(void* const* d_in, const int* in_sizes, int n_in,
                              void* d_out, int out_size, void* d_ws, size_t ws_size,
                              hipStream_t stream) {
  const float* audio   = (const float*)d_in[0];
  const int*   dstep   = (const int*)d_in[1];
  const float* W_in    = (const float*)d_in[2];
  const float* b_in    = (const float*)d_in[3];
  const float* demb_w1 = (const float*)d_in[4];
  const float* demb_b1 = (const float*)d_in[5];
  const float* demb_w2 = (const float*)d_in[6];
  const float* demb_b2 = (const float*)d_in[7];
  const float* dproj_w = (const float*)d_in[8];
  const float* dproj_b = (const float*)d_in[9];
  const float* conv_w  = (const float*)d_in[10];
  const float* conv_b  = (const float*)d_in[11];
  const float* skip_w  = (const float*)d_in[12];
  const float* skip_b  = (const float*)d_in[13];
  const float* res_w   = (const float*)d_in[14];
  const float* res_b   = (const float*)d_in[15];
  const float* W_out   = (const float*)d_in[16];
  const float* b_out   = (const float*)d_in[17];
  float* out = (float*)d_out;
  float* ws = (float*)d_ws;

  float* proj  = ws;                  // 10*4*64      = 2560
  float* skipT = proj + 2560;         // 10*64*64     = 40960
  float* resT  = skipT + 40960;       // 40960
  float* x     = resT + 40960;        // 4*4*64*4096  = 4194304
  float* y     = x + 4194304;         // 4194304
  float* tskip = y + 4194304;         // 4194304

  transpose_w_kernel<<<10, 256, 0, stream>>>(skip_w, res_w, skipT, resT);
  proj_kernel<<<10, 256, 0, stream>>>(dstep, demb_w1, demb_b1, demb_w2, demb_b2,
                                      dproj_w, dproj_b, proj);
  encode_lif_kernel<<<dim3(16, 4), 256, 0, stream>>>(audio, W_in, b_in, x);
  for (int i = 0; i < NLAYERS; ++i) {
    int dil = 1 << (i % 10);
    layer_conv_kernel<<<dim3(64, 4, 4), 256, 0, stream>>>(x, conv_w, conv_b,
                                                          proj, y, i, dil);
    skip_res_kernel<<<dim3(64, 4, 4), 256, 0, stream>>>(y, skipT, resT, skip_b,
                                                        res_b, tskip, x, i);
  }
  out_kernel<<<dim3(16, 4), 256, 0, stream>>>(tskip, W_out, b_out, out);
}

// Round 2
// 994.585 us; speedup vs baseline: 1.3081x; 1.3081x over previous
//
#include <hip/hip_runtime.h>

#define LL 4096
#define NB 4
#define NC 64
#define NT 4
#define NLAYERS 10
#define XS 5120   // padded x row stride
#define XPAD 512  // left/right zero pad (>= max dilation)

// ---------------- Threefry-2x32, key = (0, 42), 20 rounds ----------------
__device__ __forceinline__ void threefry2x32(unsigned x0, unsigned x1,
                                             unsigned& o0, unsigned& o1) {
  const unsigned ks0 = 0u, ks1 = 42u;
  const unsigned ks2 = 0x1BD11BDAu ^ ks0 ^ ks1;
  const unsigned ks[3] = {ks0, ks1, ks2};
  const unsigned r0[4] = {13u, 15u, 26u, 6u};
  const unsigned r1[4] = {17u, 29u, 16u, 24u};
  x0 += ks0; x1 += ks1;
#pragma unroll
  for (int g = 0; g < 5; ++g) {
    const unsigned* rr = (g & 1) ? r1 : r0;
#pragma unroll
    for (int j = 0; j < 4; ++j) {
      x0 += x1;
      unsigned r = rr[j];
      x1 = (x1 << r) | (x1 >> (32u - r));
      x1 ^= x0;
    }
    x0 += ks[(g + 1) % 3];
    x1 += ks[(g + 2) % 3] + (unsigned)(g + 1);
  }
  o0 = x0; o1 = x1;
}

__device__ __forceinline__ float u01(unsigned bits) {
  return __uint_as_float((bits >> 9) | 0x3f800000u) - 1.0f;
}

// LIF step: v = v + (x - v)/1.2 ; spike = v>=0.5 ; v *= (1-spike)
__device__ __forceinline__ float lif_step(float& v, float xt) {
  v = v + (xt - v) / 1.2f;
  float s = (v >= 0.5f) ? 1.0f : 0.0f;
  v = v * (1.0f - s);
  return s;
}

// ---------------- transpose skip_w / res_w to [i][c'][c] ----------------
__global__ void transpose_w_kernel(const float* __restrict__ skip_w,
                                   const float* __restrict__ res_w,
                                   float* __restrict__ skipT,
                                   float* __restrict__ resT) {
  int i = blockIdx.x;
  for (int idx = threadIdx.x; idx < 4096; idx += 256) {
    int c = idx >> 6, cp = idx & 63;
    skipT[i * 4096 + cp * 64 + c] = skip_w[i * 4096 + c * 64 + cp];
    resT[i * 4096 + cp * 64 + c] = res_w[i * 4096 + c * 64 + cp];
  }
}

// ---------------- diffusion-step embedding -> proj[i][b][c] ----------------
__global__ void proj_kernel(const int* __restrict__ dstep,
                            const float* __restrict__ w1, const float* __restrict__ b1,
                            const float* __restrict__ w2, const float* __restrict__ b2,
                            const float* __restrict__ pw, const float* __restrict__ pb,
                            float* __restrict__ proj) {
  __shared__ float e1[NB][NC];
  __shared__ float e2[NB][NC];
  int i = blockIdx.x;
  int tid = threadIdx.x;
  int b = tid >> 6, c = tid & 63;
  float d = (float)dstep[b];
  float v = d * w1[i * 64 + c] + b1[i * 64 + c];
  v = v / (1.0f + expf(-v));  // silu
  e1[b][c] = v;
  __syncthreads();
  float a = b2[i * 64 + c];
  for (int cp = 0; cp < 64; ++cp) a += e1[b][cp] * w2[(i * 64 + c) * 64 + cp];
  e2[b][c] = a;
  __syncthreads();
  float p = pb[i * 64 + c];
  for (int cp = 0; cp < 64; ++cp) p += e2[b][cp] * pw[(i * 64 + c) * 64 + cp];
  proj[(i * 4 + b) * 64 + c] = p;
}

// ---------------- per-(layer,b,co) proj-weighted tap sums S0,S1,S2 ----------------
__global__ void pc_kernel(const float* __restrict__ proj,
                          const float* __restrict__ conv_w,
                          float* __restrict__ pc) {
  __shared__ float pv[64];
  int layer = blockIdx.x, b = blockIdx.y;
  int tid = threadIdx.x;  // 128
  if (tid < 64) pv[tid] = proj[(layer * 4 + b) * 64 + tid];
  __syncthreads();
  int co = tid;
  const float* w = conv_w + (layer * 128 + co) * 192;
  float s0 = 0.0f, s1 = 0.0f, s2 = 0.0f;
  for (int ci = 0; ci < 64; ++ci) {
    float p = pv[ci];
    s0 += p * w[ci * 3 + 0];
    s1 += p * w[ci * 3 + 1];
    s2 += p * w[ci * 3 + 2];
  }
  float* o = pc + ((layer * 4 + b) * 128 + co) * 3;
  o[0] = s0; o[1] = s1; o[2] = s2;
}

// ---------------- zero the pad margins of x (ws is poisoned every call) ---------
__global__ void padzero_kernel(float* __restrict__ x) {
  int row = blockIdx.x;  // 1024 rows = T*B*C
  float* base = x + (size_t)row * XS;
  for (int i = threadIdx.x; i < XPAD; i += 256) {
    base[i] = 0.0f;
    base[XPAD + LL + i] = 0.0f;
  }
}

// ---------------- Poisson encode + input conv + LIF -> x [T][B][C][XS] ---------
__global__ void encode_lif_kernel(const float* __restrict__ audio,
                                  const float* __restrict__ W_in,
                                  const float* __restrict__ b_in,
                                  float* __restrict__ x) {
  int tid = threadIdx.x;
  int lq = tid & 63, grp = tid >> 6;
  int l = blockIdx.x * 64 + lq;
  int b = blockIdx.y;
  float a = audio[b * LL + l];
  unsigned p0 = (unsigned)(b * LL + l);  // t=0 (o0), t=2 (o1)
  unsigned p1 = 16384u + p0;             // t=1 (o0), t=3 (o1)
  unsigned o00, o01, o10, o11;
  threefry2x32(p0, p0 + 32768u, o00, o01);
  threefry2x32(p1, p1 + 32768u, o10, o11);
  float sp[4];
  sp[0] = (u01(o00) < a) ? 1.0f : 0.0f;
  sp[1] = (u01(o10) < a) ? 1.0f : 0.0f;
  sp[2] = (u01(o01) < a) ? 1.0f : 0.0f;
  sp[3] = (u01(o11) < a) ? 1.0f : 0.0f;
  for (int j = 0; j < 16; ++j) {
    int c = grp * 16 + j;
    float w = W_in[c], bb = b_in[c];
    float v = 0.0f;
#pragma unroll
    for (int t = 0; t < 4; ++t) {
      float s = lif_step(v, w * sp[t] + bb);
      x[(size_t)((t * 4 + b) * 64 + c) * XS + XPAD + l] = s;
    }
  }
}

// ---------------- dilated conv + LIF + gate -> y [T][B][64][L] ----------------
// grid (16, 8, 4): l-tile 256, co-group g (gate co g*8..g*8+8, filt +64), b.
// block 256; each thread: 1 l, 4 t, 8 gate + 8 filt co. proj folded into bias.
template <int DIL>
__global__ __launch_bounds__(256) void layer_conv_kernel(
    const float* __restrict__ x, const float* __restrict__ conv_w,
    const float* __restrict__ conv_b, const float* __restrict__ pc,
    float* __restrict__ y, int layer) {
  __shared__ float w_lds[192 * 16];  // [ci*3+k][col] col: 0-7 gate, 8-15 filt
  __shared__ float b_lds[16], s0_lds[16], s2_lds[16];
  int tid = threadIdx.x;
  int g = blockIdx.y;
  int b = blockIdx.z;
  int l = blockIdx.x * 256 + tid;

  for (int idx = tid; idx < 3072; idx += 256) {
    int r = idx % 192;     // ci*3+k
    int col = idx / 192;   // 0..15
    int co = (col < 8) ? (g * 8 + col) : (64 + g * 8 + (col - 8));
    w_lds[r * 16 + col] = conv_w[(layer * 128 + co) * 192 + r];
  }
  if (tid < 16) {
    int col = tid;
    int co = (col < 8) ? (g * 8 + col) : (64 + g * 8 + (col - 8));
    const float* p = pc + ((layer * 4 + b) * 128 + co) * 3;
    float S0 = p[0], S1 = p[1], S2 = p[2];
    b_lds[col] = conv_b[layer * 128 + co] + S0 + S1 + S2;
    s0_lds[col] = S0;
    s2_lds[col] = S2;
  }
  __syncthreads();

  const float* px[4];
#pragma unroll
  for (int t = 0; t < 4; ++t)
    px[t] = x + (size_t)((t * 4 + b) * 64) * XS + XPAD + l;

  float ag[32], af[32];  // [t*8+j]
#pragma unroll
  for (int q = 0; q < 32; ++q) { ag[q] = 0.0f; af[q] = 0.0f; }

  float xc[12], xn[12];  // [t*3+k]
  auto load12 = [&](float* dst) {
#pragma unroll
    for (int t = 0; t < 4; ++t) {
      dst[t * 3 + 0] = px[t][-DIL];
      dst[t * 3 + 1] = px[t][0];
      dst[t * 3 + 2] = px[t][DIL];
      px[t] += XS;
    }
  };
  auto compute = [&](int ci, const float* xv) {
#pragma unroll
    for (int k = 0; k < 3; ++k) {
      const float4 wg0 = *(const float4*)&w_lds[(ci * 3 + k) * 16 + 0];
      const float4 wg1 = *(const float4*)&w_lds[(ci * 3 + k) * 16 + 4];
      const float4 wf0 = *(const float4*)&w_lds[(ci * 3 + k) * 16 + 8];
      const float4 wf1 = *(const float4*)&w_lds[(ci * 3 + k) * 16 + 12];
#pragma unroll
      for (int t = 0; t < 4; ++t) {
        float xq = xv[t * 3 + k];
        ag[t * 8 + 0] += wg0.x * xq; ag[t * 8 + 1] += wg0.y * xq;
        ag[t * 8 + 2] += wg0.z * xq; ag[t * 8 + 3] += wg0.w * xq;
        ag[t * 8 + 4] += wg1.x * xq; ag[t * 8 + 5] += wg1.y * xq;
        ag[t * 8 + 6] += wg1.z * xq; ag[t * 8 + 7] += wg1.w * xq;
        af[t * 8 + 0] += wf0.x * xq; af[t * 8 + 1] += wf0.y * xq;
        af[t * 8 + 2] += wf0.z * xq; af[t * 8 + 3] += wf0.w * xq;
        af[t * 8 + 4] += wf1.x * xq; af[t * 8 + 5] += wf1.y * xq;
        af[t * 8 + 6] += wf1.z * xq; af[t * 8 + 7] += wf1.w * xq;
      }
    }
  };

  load12(xc);
  for (int ci = 0; ci < 64; ci += 2) {
    load12(xn);                       // data for ci+1
    compute(ci, xc);
    if (ci + 2 < 64) load12(xc);      // data for ci+2
    compute(ci + 1, xn);
  }

  const float SIG1 = 0.73105857863000489f;   // sigmoid(1) fp32
  const float TANH1 = 0.76159415595576486f;  // tanh(1) fp32
  bool lb = (l < DIL), rb = (l >= LL - DIL);
#pragma unroll
  for (int j = 0; j < 8; ++j) {
    int cg = g * 8 + j;
    float bg = b_lds[j] - (lb ? s0_lds[j] : 0.0f) - (rb ? s2_lds[j] : 0.0f);
    float bf = b_lds[8 + j] - (lb ? s0_lds[8 + j] : 0.0f) - (rb ? s2_lds[8 + j] : 0.0f);
    float vg = 0.0f, vf = 0.0f;
#pragma unroll
    for (int t = 0; t < 4; ++t) {
      float sg = lif_step(vg, ag[t * 8 + j] + bg);
      float sf = lif_step(vf, af[t * 8 + j] + bf);
      float gv = (sg != 0.0f) ? SIG1 : 0.5f;
      float tv = (sf != 0.0f) ? TANH1 : 0.0f;
      y[(size_t)((t * 4 + b) * 64 + cg) * LL + l] = gv * tv;
    }
  }
}

// ---------------- fused 1x1 skip & res convs ----------------
// grid (32, 4, 4): l-tile 128, t, b. block 256 = 4 waves.
// thread: 2 l (lane*2), 16 c (wave*16..), both skip and res.
__global__ __launch_bounds__(256) void skip_res_kernel(
    const float* __restrict__ y, const float* __restrict__ skipT,
    const float* __restrict__ resT, const float* __restrict__ skip_b,
    const float* __restrict__ res_b, float* __restrict__ tskip,
    float* __restrict__ x, int layer) {
  __shared__ float sw[4096];  // [c'][c]
  __shared__ float rw[4096];
  int tid = threadIdx.x;
  int lane = tid & 63, wave = tid >> 6;
  int c0 = wave * 16;
  int l0 = blockIdx.x * 128;
  int t = blockIdx.y;
  int b = blockIdx.z;

  {
    const float4* s4 = (const float4*)(skipT + layer * 4096);
    const float4* r4 = (const float4*)(resT + layer * 4096);
    for (int idx = tid; idx < 1024; idx += 256) {
      ((float4*)sw)[idx] = s4[idx];
      ((float4*)rw)[idx] = r4[idx];
    }
  }
  __syncthreads();

  float s0a[16], s1a[16], r0a[16], r1a[16];
#pragma unroll
  for (int j = 0; j < 16; ++j) { s0a[j] = 0.0f; s1a[j] = 0.0f; r0a[j] = 0.0f; r1a[j] = 0.0f; }

  const float* ybase = y + (size_t)((t * 4 + b) * 64) * LL + l0 + lane * 2;
  float2 yv = *(const float2*)ybase;
  for (int cp = 0; cp < 64; ++cp) {
    float2 ynx = (cp < 63) ? *(const float2*)(ybase + (size_t)(cp + 1) * LL) : yv;
#pragma unroll
    for (int q = 0; q < 4; ++q) {
      const float4 ws = *(const float4*)&sw[cp * 64 + c0 + q * 4];
      const float4 wr = *(const float4*)&rw[cp * 64 + c0 + q * 4];
      s0a[q * 4 + 0] += ws.x * yv.x; s1a[q * 4 + 0] += ws.x * yv.y;
      s0a[q * 4 + 1] += ws.y * yv.x; s1a[q * 4 + 1] += ws.y * yv.y;
      s0a[q * 4 + 2] += ws.z * yv.x; s1a[q * 4 + 2] += ws.z * yv.y;
      s0a[q * 4 + 3] += ws.w * yv.x; s1a[q * 4 + 3] += ws.w * yv.y;
      r0a[q * 4 + 0] += wr.x * yv.x; r1a[q * 4 + 0] += wr.x * yv.y;
      r0a[q * 4 + 1] += wr.y * yv.x; r1a[q * 4 + 1] += wr.y * yv.y;
      r0a[q * 4 + 2] += wr.z * yv.x; r1a[q * 4 + 2] += wr.z * yv.y;
      r0a[q * 4 + 3] += wr.w * yv.x; r1a[q * 4 + 3] += wr.w * yv.y;
    }
    yv = ynx;
  }

#pragma unroll
  for (int j = 0; j < 16; ++j) {
    int c = c0 + j;
    float sb = skip_b[layer * 64 + c];
    float rb = res_b[layer * 64 + c];
    size_t idxT = (size_t)((t * 4 + b) * 64 + c) * LL + l0 + lane * 2;
    float2 tv;
    if (layer == 0) { tv.x = 0.0f; tv.y = 0.0f; }
    else tv = *(const float2*)&tskip[idxT];
    tv.x += s0a[j] + sb;
    tv.y += s1a[j] + sb;
    *(float2*)&tskip[idxT] = tv;
    size_t idxX = (size_t)((t * 4 + b) * 64 + c) * XS + XPAD + l0 + lane * 2;
    float2 xv = *(const float2*)&x[idxX];
    xv.x += r0a[j] + rb;
    xv.y += r1a[j] + rb;
    *(float2*)&x[idxX] = xv;
  }
}

// ---------------- output conv + LIF + sum over T ----------------
__global__ void out_kernel(const float* __restrict__ tskip,
                           const float* __restrict__ W_out,
                           const float* __restrict__ b_out,
                           float* __restrict__ out) {
  __shared__ float red[4][4][64];  // [grp][t][lq]
  int tid = threadIdx.x;
  int lq = tid & 63, grp = tid >> 6;
  int l = blockIdx.x * 64 + lq;
  int b = blockIdx.y;
  float acc[4] = {0.0f, 0.0f, 0.0f, 0.0f};
  for (int j = 0; j < 16; ++j) {
    int c = grp * 16 + j;
    float w = W_out[c];
#pragma unroll
    for (int t = 0; t < 4; ++t) {
      float sv = tskip[(size_t)((t * 4 + b) * 64 + c) * LL + l];
      acc[t] += fmaxf(sv, 0.0f) * w;
    }
  }
#pragma unroll
  for (int t = 0; t < 4; ++t) red[grp][t][lq] = acc[t];
  __syncthreads();
  if (grp == 0) {
    float bo = b_out[0];
    float v = 0.0f, s = 0.0f;
#pragma unroll
    for (int t = 0; t < 4; ++t) {
      float a = red[0][t][lq] + red[1][t][lq] + red[2][t][lq] + red[3][t][lq] + bo;
      s += lif_step(v, a);
    }
    out[b * LL + l] = s;
  }
}

extern "C" void kernel_launch(void* const* d_in, const int* in_sizes, int n_in,
                              void* d_out, int out_size, void* d_ws, size_t ws_size,
                              hipStream_t stream) {
  const float* audio   = (const float*)d_in[0];
  const int*   dstep   = (const int*)d_in[1];
  const float* W_in    = (const float*)d_in[2];
  const float* b_in    = (const float*)d_in[3];
  const float* demb_w1 = (const float*)d_in[4];
  const float* demb_b1 = (const float*)d_in[5];
  const float* demb_w2 = (const float*)d_in[6];
  const float* demb_b2 = (const float*)d_in[7];
  const float* dproj_w = (const float*)d_in[8];
  const float* dproj_b = (const float*)d_in[9];
  const float* conv_w  = (const float*)d_in[10];
  const float* conv_b  = (const float*)d_in[11];
  const float* skip_w  = (const float*)d_in[12];
  const float* skip_b  = (const float*)d_in[13];
  const float* res_w   = (const float*)d_in[14];
  const float* res_b   = (const float*)d_in[15];
  const float* W_out   = (const float*)d_in[16];
  const float* b_out   = (const float*)d_in[17];
  float* out = (float*)d_out;
  float* ws = (float*)d_ws;

  float* proj  = ws;                   // 2560
  float* skipT = proj + 2560;          // 40960
  float* resT  = skipT + 40960;        // 40960
  float* pc    = resT + 40960;         // 10*4*128*3 = 15360
  float* x     = pc + 15360;           // 4*4*64*5120 = 5242880
  float* y     = x + 5242880;          // 4194304
  float* tskip = y + 4194304;          // 4194304

  transpose_w_kernel<<<10, 256, 0, stream>>>(skip_w, res_w, skipT, resT);
  proj_kernel<<<10, 256, 0, stream>>>(dstep, demb_w1, demb_b1, demb_w2, demb_b2,
                                      dproj_w, dproj_b, proj);
  pc_kernel<<<dim3(10, 4), 128, 0, stream>>>(proj, conv_w, pc);
  padzero_kernel<<<1024, 256, 0, stream>>>(x);
  encode_lif_kernel<<<dim3(64, 4), 256, 0, stream>>>(audio, W_in, b_in, x);

  for (int i = 0; i < NLAYERS; ++i) {
    dim3 gc(16, 8, 4);
    switch (i) {
      case 0: layer_conv_kernel<1><<<gc, 256, 0, stream>>>(x, conv_w, conv_b, pc, y, i); break;
      case 1: layer_conv_kernel<2><<<gc, 256, 0, stream>>>(x, conv_w, conv_b, pc, y, i); break;
      case 2: layer_conv_kernel<4><<<gc, 256, 0, stream>>>(x, conv_w, conv_b, pc, y, i); break;
      case 3: layer_conv_kernel<8><<<gc, 256, 0, stream>>>(x, conv_w, conv_b, pc, y, i); break;
      case 4: layer_conv_kernel<16><<<gc, 256, 0, stream>>>(x, conv_w, conv_b, pc, y, i); break;
      case 5: layer_conv_kernel<32><<<gc, 256, 0, stream>>>(x, conv_w, conv_b, pc, y, i); break;
      case 6: layer_conv_kernel<64><<<gc, 256, 0, stream>>>(x, conv_w, conv_b, pc, y, i); break;
      case 7: layer_conv_kernel<128><<<gc, 256, 0, stream>>>(x, conv_w, conv_b, pc, y, i); break;
      case 8: layer_conv_kernel<256><<<gc, 256, 0, stream>>>(x, conv_w, conv_b, pc, y, i); break;
      case 9: layer_conv_kernel<512><<<gc, 256, 0, stream>>>(x, conv_w, conv_b, pc, y, i); break;
    }
    skip_res_kernel<<<dim3(32, 4, 4), 256, 0, stream>>>(y, skipT, resT, skip_b,
                                                        res_b, tskip, x, i);
  }
  out_kernel<<<dim3(64, 4), 256, 0, stream>>>(tskip, W_out, b_out, out);
}